// Round 1
// baseline (2380.781 us; speedup 1.0000x reference)
//
#include <hip/hip_runtime.h>
#include <math.h>

// ---------------------------------------------------------------------------
// VQ-VAE forward, fp32 direct implementation.
// Shapes: B=128, L=4096, H=128, RH=64, D=64, K=512.
// ---------------------------------------------------------------------------

// Generic 1D conv, NCW layout.
// out[b,co,l] = bias[co] + sum_{ci,k} in[b,ci, l*STRIDE - PAD + k] * w[co,ci,k]
// Tile: 64 output positions per block; 4 waves x 8 channels register blocking.
template<int K, int STRIDE, int PAD, bool RELU_IN, bool RELU_OUT, bool ACC, bool HAS_BIAS, int SMEM>
__global__ __launch_bounds__(256) void conv1d_k(
    const float* __restrict__ in, const float* __restrict__ w,
    const float* __restrict__ bias, float* __restrict__ out,
    int Cin, int Lin, int Cout, int Lout)
{
    constexpr int LT = 64;
    constexpr int IT = LT * STRIDE + K;           // input span staged per block
    __shared__ float sIn[SMEM];                   // SMEM == Cin*IT for the instantiation
    const int tid = threadIdx.x;
    const int b  = blockIdx.y;
    const int l0 = blockIdx.x * LT;
    const float* inb = in + (size_t)b * Cin * Lin;
    const int tot = Cin * IT;
    const int g0  = l0 * STRIDE - PAD;

    for (int i = tid; i < tot; i += 256) {
        int ci = i / IT;                          // IT is compile-time -> magic mul
        int p  = i - ci * IT;
        int gp = g0 + p;
        float v = 0.f;
        if (gp >= 0 && gp < Lin) v = inb[(size_t)ci * Lin + gp];
        if (RELU_IN) v = fmaxf(v, 0.f);
        sIn[i] = v;
    }
    __syncthreads();

    const int lane = tid & 63;
    const int wid  = __builtin_amdgcn_readfirstlane(tid >> 6);  // force SGPR
    const int l = l0 + lane;                      // Lout is always a multiple of 64
    float* outb = out + (size_t)b * Cout * Lout + l;

    for (int co0 = wid * 8; co0 < Cout; co0 += 32) {
        float acc[8];
#pragma unroll
        for (int j = 0; j < 8; ++j) acc[j] = HAS_BIAS ? bias[co0 + j] : 0.f;
        const float* wb = w + (size_t)co0 * Cin * K;
        for (int ci = 0; ci < Cin; ++ci) {
#pragma unroll
            for (int k = 0; k < K; ++k) {
                const float v = sIn[ci * IT + lane * STRIDE + k];
#pragma unroll
                for (int j = 0; j < 8; ++j)
                    acc[j] = fmaf(v, wb[(size_t)j * Cin * K + ci * K + k], acc[j]);
            }
        }
#pragma unroll
        for (int j = 0; j < 8; ++j) {
            float r = acc[j];
            if (RELU_OUT) r = fmaxf(r, 0.f);
            float* po = outb + (size_t)(co0 + j) * Lout;
            if (ACC) r += *po;
            *po = r;
        }
    }
}

// Transposed conv, stride=2, pad=1, K=4, w layout (Cin, Cout, 4).
// out[b,co,2m]   = bias + sum_ci x[m]  *w[ci,co,1] + x[m-1]*w[ci,co,3]
// out[b,co,2m+1] = bias + sum_ci x[m+1]*w[ci,co,0] + x[m]  *w[ci,co,2]
template<bool RELU_IN, bool RELU_OUT, int SMEM>
__global__ __launch_bounds__(256) void convT_k(
    const float* __restrict__ in, const float* __restrict__ w,
    const float* __restrict__ bias, float* __restrict__ out,
    int Cin, int Lin, int Cout)
{
    constexpr int MT = 64;
    constexpr int IT = MT + 2;                    // m0-1 .. m0+64
    __shared__ float sIn[SMEM];
    const int tid = threadIdx.x;
    const int b  = blockIdx.y;
    const int m0 = blockIdx.x * MT;
    const float* inb = in + (size_t)b * Cin * Lin;
    const int tot = Cin * IT;
    for (int i = tid; i < tot; i += 256) {
        int ci = i / IT;
        int p  = i - ci * IT;
        int gm = m0 - 1 + p;
        float v = 0.f;
        if (gm >= 0 && gm < Lin) v = inb[(size_t)ci * Lin + gm];
        if (RELU_IN) v = fmaxf(v, 0.f);
        sIn[i] = v;
    }
    __syncthreads();

    const int lane = tid & 63;
    const int wid  = __builtin_amdgcn_readfirstlane(tid >> 6);
    const int m = m0 + lane;
    const int Lout = 2 * Lin;
    float* outb = out + (size_t)b * Cout * Lout + 2 * m;

    for (int co0 = wid * 8; co0 < Cout; co0 += 32) {
        float ae[8], ao[8];
#pragma unroll
        for (int j = 0; j < 8; ++j) {
            float bv = (co0 + j < Cout) ? bias[co0 + j] : 0.f;
            ae[j] = bv; ao[j] = bv;
        }
        for (int ci = 0; ci < Cin; ++ci) {
            const float xm1 = sIn[ci * IT + lane];
            const float x0  = sIn[ci * IT + lane + 1];
            const float xp1 = sIn[ci * IT + lane + 2];
            const float* wc = w + ((size_t)ci * Cout + co0) * 4;
#pragma unroll
            for (int j = 0; j < 8; ++j) {
                if (co0 + j < Cout) {
                    ae[j] = fmaf(x0,  wc[j*4+1], fmaf(xm1, wc[j*4+3], ae[j]));
                    ao[j] = fmaf(xp1, wc[j*4+0], fmaf(x0,  wc[j*4+2], ao[j]));
                }
            }
        }
#pragma unroll
        for (int j = 0; j < 8; ++j) {
            if (co0 + j < Cout) {
                float e = ae[j], o = ao[j];
                if (RELU_OUT) { e = fmaxf(e, 0.f); o = fmaxf(o, 0.f); }
                *(float2*)(outb + (size_t)(co0 + j) * Lout) = make_float2(e, o);
            }
        }
    }
}

// codebook squared norms
__global__ __launch_bounds__(256) void cbnorm_k(const float* __restrict__ cb,
                                                float* __restrict__ sc)
{
    int k = blockIdx.x * 256 + threadIdx.x;
    if (k < 512) {
        float s = 0.f;
        const float* c = cb + (size_t)k * 64;
#pragma unroll
        for (int d = 0; d < 64; ++d) s = fmaf(c[d], c[d], s);
        sc[k] = s;
    }
}

// VQ: per position n=(b,l): argmin_k ||f - c_k||^2 via sf - 2 f.c + sc[k];
// writes q (NCW), idx, histogram counts, and accumulates sum((q-f)^2).
__global__ __launch_bounds__(256) void vq_k(
    const float* __restrict__ z, const float* __restrict__ cb,
    const float* __restrict__ sc, float* __restrict__ qt,
    int* __restrict__ idx_out, float* __restrict__ counts,
    float* __restrict__ loss_sum)
{
    __shared__ float hcnt[512];
    __shared__ float wsum[4];
    const int tid = threadIdx.x;
    hcnt[tid] = 0.f; hcnt[tid + 256] = 0.f;

    const int n = blockIdx.x * 256 + tid;
    const int b = n >> 10;
    const int l = n & 1023;
    const float* zb = z + (size_t)b * 65536 + l;
    float f[64];
#pragma unroll
    for (int d = 0; d < 64; ++d) f[d] = zb[(size_t)d * 1024];
    float sf = 0.f;
#pragma unroll
    for (int d = 0; d < 64; ++d) sf = fmaf(f[d], f[d], sf);

    float best = 3.4e38f; int bk = 0;
    for (int k = 0; k < 512; ++k) {               // k wave-uniform -> scalar loads
        const float* ck = cb + (size_t)k * 64;
        float dot = 0.f;
#pragma unroll
        for (int d = 0; d < 64; ++d) dot = fmaf(f[d], ck[d], dot);
        float dist = sf - 2.f * dot + sc[k];
        if (dist < best) { best = dist; bk = k; } // strict < keeps first min (argmin)
    }
    idx_out[n] = bk;
    __syncthreads();                              // hcnt init visible
    atomicAdd(&hcnt[bk], 1.f);

    float lsum = 0.f;
    const float* cbk = cb + (size_t)bk * 64;
    float* qb = qt + (size_t)b * 65536 + l;
#pragma unroll
    for (int d = 0; d < 64; ++d) {
        float qv = cbk[d];
        qb[(size_t)d * 1024] = qv;
        float df = qv - f[d];
        lsum = fmaf(df, df, lsum);
    }
#pragma unroll
    for (int off = 32; off > 0; off >>= 1) lsum += __shfl_down(lsum, off, 64);
    const int lane = tid & 63, wid = tid >> 6;
    if (lane == 0) wsum[wid] = lsum;
    __syncthreads();                              // hcnt atomics + wsum complete
    if (tid == 0) atomicAdd(loss_sum, wsum[0] + wsum[1] + wsum[2] + wsum[3]);
    float c0 = hcnt[tid];       if (c0 != 0.f) atomicAdd(&counts[tid], c0);
    float c1 = hcnt[tid + 256]; if (c1 != 0.f) atomicAdd(&counts[tid + 256], c1);
}

__global__ __launch_bounds__(512) void finalize_k(
    const float* __restrict__ counts, const float* __restrict__ loss_sum,
    float* __restrict__ d_out, int out_size)
{
    __shared__ float ws2[8];
    const int tid = threadIdx.x;
    float p = counts[tid] * (1.f / 131072.f);
    float e = p * logf(p + 1e-10f);
#pragma unroll
    for (int off = 32; off > 0; off >>= 1) e += __shfl_down(e, off, 64);
    const int lane = tid & 63, wid = tid >> 6;
    if (lane == 0) ws2[wid] = e;
    __syncthreads();
    if (tid == 0) {
        float s = 0.f;
        for (int i = 0; i < 8; ++i) s += ws2[i];
        d_out[0] = 1.25f * loss_sum[0] * (1.f / 8388608.f);  // (1+BETA)*mean
        d_out[out_size - 1] = expf(-s);
    }
}

extern "C" void kernel_launch(void* const* d_in, const int* in_sizes, int n_in,
                              void* d_out, int out_size, void* d_ws, size_t ws_size,
                              hipStream_t stream)
{
    const float* x        = (const float*)d_in[0];
    const float* enc_w1   = (const float*)d_in[1];
    const float* enc_b1   = (const float*)d_in[2];
    const float* enc_w2   = (const float*)d_in[3];
    const float* enc_b2   = (const float*)d_in[4];
    const float* enc_w3   = (const float*)d_in[5];
    const float* enc_b3   = (const float*)d_in[6];
    const float* enc_r1a  = (const float*)d_in[7];
    const float* enc_r1b  = (const float*)d_in[8];
    const float* enc_r2a  = (const float*)d_in[9];
    const float* enc_r2b  = (const float*)d_in[10];
    const float* pre_vq_w = (const float*)d_in[11];
    const float* pre_vq_b = (const float*)d_in[12];
    const float* cb       = (const float*)d_in[13];
    const float* dec_w1   = (const float*)d_in[14];
    const float* dec_b1   = (const float*)d_in[15];
    const float* dec_r1a  = (const float*)d_in[16];
    const float* dec_r1b  = (const float*)d_in[17];
    const float* dec_r2a  = (const float*)d_in[18];
    const float* dec_r2b  = (const float*)d_in[19];
    const float* ct1_w    = (const float*)d_in[20];
    const float* ct1_b    = (const float*)d_in[21];
    const float* ct2_w    = (const float*)d_in[22];
    const float* ct2_b    = (const float*)d_in[23];
    float* out = (float*)d_out;
    float* ws  = (float*)d_ws;

    // Workspace layout (floats). Peak usage ~134.8 MB.
    float* A    = ws;                       // 16,777,216  (B,64,2048) or (B,128,1024)
    float* X    = ws + 16777216;            // 16,777,216
    int*   idx  = (int*)(ws + 33554432);    // 131072
    float* sc   = ws + 33685504;            // 512
    float* cnt  = ws + 33686016;            // 512
    float* lsum = ws + 33686528;            // 1
    float* Z    = X + 8388608;              // (B,64,1024) second half of X
    float* QT   = X;                        // (B,64,1024) first half of X
    float* E    = X;                        // res-stack hidden, first half of X

    hipMemsetAsync(cnt, 0, 513 * sizeof(float), stream);  // counts + loss accum

    dim3 blk(256);
    // encoder
    conv1d_k<4,2,1,false,true ,false,true ,  132><<<dim3(32,128),blk,0,stream>>>(x,  enc_w1, enc_b1, A, 1,  4096, 64, 2048);
    conv1d_k<4,2,1,false,true ,false,true , 8448><<<dim3(16,128),blk,0,stream>>>(A,  enc_w2, enc_b2, X, 64, 2048,128, 1024);
    conv1d_k<3,1,1,false,false,false,true , 8576><<<dim3(16,128),blk,0,stream>>>(X,  enc_w3, enc_b3, A, 128,1024,128, 1024);
    conv1d_k<3,1,1,true ,false,false,false, 8576><<<dim3(16,128),blk,0,stream>>>(A,  enc_r1a, nullptr, E, 128,1024, 64, 1024);
    conv1d_k<1,1,0,true ,false,true ,false, 4160><<<dim3(16,128),blk,0,stream>>>(E,  enc_r1b, nullptr, A, 64, 1024,128, 1024);
    conv1d_k<3,1,1,true ,false,false,false, 8576><<<dim3(16,128),blk,0,stream>>>(A,  enc_r2a, nullptr, E, 128,1024, 64, 1024);
    conv1d_k<1,1,0,true ,false,true ,false, 4160><<<dim3(16,128),blk,0,stream>>>(E,  enc_r2b, nullptr, A, 64, 1024,128, 1024);
    conv1d_k<1,1,0,true ,false,false,true , 8320><<<dim3(16,128),blk,0,stream>>>(A,  pre_vq_w, pre_vq_b, Z, 128,1024, 64, 1024);
    // VQ
    cbnorm_k<<<2, 256, 0, stream>>>(cb, sc);
    vq_k<<<512, 256, 0, stream>>>(Z, cb, sc, QT, idx, cnt, lsum);
    // decoder
    conv1d_k<3,1,1,false,false,false,true , 4288><<<dim3(16,128),blk,0,stream>>>(QT, dec_w1, dec_b1, A, 64, 1024,128, 1024);
    conv1d_k<3,1,1,true ,false,false,false, 8576><<<dim3(16,128),blk,0,stream>>>(A,  dec_r1a, nullptr, E, 128,1024, 64, 1024);
    conv1d_k<1,1,0,true ,false,true ,false, 4160><<<dim3(16,128),blk,0,stream>>>(E,  dec_r1b, nullptr, A, 64, 1024,128, 1024);
    conv1d_k<3,1,1,true ,false,false,false, 8576><<<dim3(16,128),blk,0,stream>>>(A,  dec_r2a, nullptr, E, 128,1024, 64, 1024);
    conv1d_k<1,1,0,true ,false,true ,false, 4160><<<dim3(16,128),blk,0,stream>>>(E,  dec_r2b, nullptr, A, 64, 1024,128, 1024);
    convT_k<true ,true , 8448><<<dim3(16,128),blk,0,stream>>>(A, ct1_w, ct1_b, X, 128, 1024, 64);
    convT_k<false,false, 4224><<<dim3(32,128),blk,0,stream>>>(X, ct2_w, ct2_b, out + 1, 64, 2048, 1);
    // scalars
    finalize_k<<<1, 512, 0, stream>>>(cnt, lsum, out, out_size);
}

// Round 2
// 787.463 us; speedup vs baseline: 3.0234x; 3.0234x over previous
//
#include <hip/hip_runtime.h>
#include <hip/hip_bf16.h>
#include <math.h>

using bf16 = __hip_bfloat16;
typedef __attribute__((ext_vector_type(4))) float f32x4;
typedef __attribute__((ext_vector_type(8))) short s16x8;

#define MFMA16(a,b,c) __builtin_amdgcn_mfma_f32_16x16x32_bf16((a),(b),(c),0,0,0)

// ---------------------------------------------------------------------------
// VQ-VAE forward. B=128, L=4096, H=128, RH=64, D=64, K=512.
// Mid-layer convs as bf16 MFMA GEMM-convs; VQ fp32; activations bf16.
// ---------------------------------------------------------------------------

enum { M_S1 = 0, M_S2 = 1, M_CT = 2 };

// GEMM-conv: out[b,co,l] = bias + sum_{tap,ci} Wt[tap][co][ci] * X[ci][col(l,tap)]
// Block: 256 thr (4 waves), tile COUT x 64 output cols. MFMA 16x16x32 bf16.
// A (weights) from global (L2-resident, pre-transformed bf16 [tap][co][ci]).
// B (X tile) staged in LDS [t][ci] bf16 with XOR swizzle (t&7)<<4 on byte addr.
template<int CIN, int COUT, int NTAP, int MODE, bool RELU_IN, bool RELU_OUT,
         bool ACC, bool HAS_BIAS, bool OUT_F32>
__global__ __launch_bounds__(256) void gconv_k(
    const bf16* __restrict__ in, const bf16* __restrict__ wt,
    const float* __restrict__ bias, void* __restrict__ outv,
    int Lin, int Lout)
{
    constexpr int T  = (MODE == M_S2) ? 132 : ((MODE == M_CT) ? 66 : (NTAP == 3 ? 66 : 64));
    constexpr int NG = (MODE == M_CT) ? 2 : 1;   // CT: even/odd output phases
    constexpr int WL = (COUT == 128) ? 4 : 2;    // l-frags per wave
    constexpr int KS = CIN / 32;                 // K-steps per tap
    __shared__ bf16 sX[T * CIN];

    const int tid = threadIdx.x;
    const int b   = blockIdx.y;
    const int l0  = blockIdx.x * 64;
    const bf16* inb = in + (size_t)b * CIN * Lin;

    // ---- stage X tile into LDS (transposed to [t][ci], swizzled) ----
    if (MODE == M_S2) {
        // even rows t=0..64: x[2(l0+t)]; odd rows t=66..130: x[2(l0+t')-1]
        for (int i = tid; i < 65 * CIN * 2; i += 256) {
            int half = i / (65 * CIN);
            int r  = i - half * 65 * CIN;
            int ci = r / 65, tt = r - ci * 65;
            int g  = half ? (2 * (l0 + tt) - 1) : (2 * (l0 + tt));
            float v = 0.f;
            if (g >= 0 && g < Lin) v = __bfloat162float(inb[(size_t)ci * Lin + g]);
            if (RELU_IN) v = fmaxf(v, 0.f);
            int t = half ? (66 + tt) : tt;
            int byte = ((t * CIN + ci) << 1) ^ ((t & 7) << 4);
            *(bf16*)((char*)sX + byte) = __float2bfloat16(v);
        }
    } else {
        constexpr int SOFF = (MODE == M_CT) ? -1 : (NTAP == 3 ? -1 : 0);
        for (int i = tid; i < T * CIN; i += 256) {
            int ci = i / T, t = i - ci * T;
            int g = l0 + t + SOFF;
            float v = 0.f;
            if (g >= 0 && g < Lin) v = __bfloat162float(inb[(size_t)ci * Lin + g]);
            if (RELU_IN) v = fmaxf(v, 0.f);
            int byte = ((t * CIN + ci) << 1) ^ ((t & 7) << 4);
            *(bf16*)((char*)sX + byte) = __float2bfloat16(v);
        }
    }
    __syncthreads();

    const int lane = tid & 63;
    const int wid  = tid >> 6;
    const int co0  = (COUT == 128) ? wid * 32 : (wid & 1) * 32;
    const int lw0  = (COUT == 128) ? 0 : (wid >> 1) * 32;
    const int lr   = lane & 15;   // A row-in-frag / B col-in-frag
    const int kg   = lane >> 4;   // k-group (8 consecutive k elems)

    f32x4 acc[NG][2][WL];
#pragma unroll
    for (int g = 0; g < NG; ++g)
#pragma unroll
        for (int cf = 0; cf < 2; ++cf)
#pragma unroll
            for (int lf = 0; lf < WL; ++lf)
                acc[g][cf][lf] = (f32x4){0.f, 0.f, 0.f, 0.f};

#pragma unroll
    for (int g = 0; g < NG; ++g) {
#pragma unroll
        for (int k = 0; k < NTAP; ++k) {
            int roff;
            if (MODE == M_S1)      roff = k;
            else if (MODE == M_S2) roff = (k == 0) ? 66 : (k == 1) ? 0 : (k == 2) ? 67 : 1;
            else                   roff = g + k;   // even taps {0,1}, odd {1,2}
            const bf16* Ab = wt + (size_t)(g * NTAP + k) * COUT * CIN;
#pragma unroll
            for (int ks = 0; ks < KS; ++ks) {
                s16x8 af[2];
#pragma unroll
                for (int cf = 0; cf < 2; ++cf)
                    af[cf] = *(const s16x8*)(Ab + (co0 + cf * 16 + lr) * CIN + ks * 32 + kg * 8);
                s16x8 bfr[WL];
#pragma unroll
                for (int lf = 0; lf < WL; ++lf) {
                    int t = roff + lw0 + lf * 16 + lr;
                    int byte = ((t * CIN + ks * 32 + kg * 8) << 1) ^ ((t & 7) << 4);
                    bfr[lf] = *(const s16x8*)((const char*)sX + byte);
                }
#pragma unroll
                for (int cf = 0; cf < 2; ++cf)
#pragma unroll
                    for (int lf = 0; lf < WL; ++lf)
                        acc[g][cf][lf] = MFMA16(af[cf], bfr[lf], acc[g][cf][lf]);
            }
        }
    }

    // ---- epilogue: D row=(lane>>4)*4+j (=co), col=lane&15 (=l) ----
#pragma unroll
    for (int g = 0; g < NG; ++g)
#pragma unroll
        for (int cf = 0; cf < 2; ++cf)
#pragma unroll
            for (int lf = 0; lf < WL; ++lf)
#pragma unroll
                for (int j = 0; j < 4; ++j) {
                    int co   = co0 + cf * 16 + kg * 4 + j;
                    int lcol = lw0 + lf * 16 + lr;
                    int gcol = (MODE == M_CT) ? (2 * (l0 + lcol) + g) : (l0 + lcol);
                    float r = acc[g][cf][lf][j];
                    if (HAS_BIAS) r += bias[co];
                    size_t oidx = (size_t)b * COUT * Lout + (size_t)co * Lout + gcol;
                    if (OUT_F32) {
                        ((float*)outv)[oidx] = r;
                    } else {
                        bf16* outp = (bf16*)outv;
                        if (ACC) r += __bfloat162float(outp[oidx]);
                        if (RELU_OUT) r = fmaxf(r, 0.f);
                        outp[oidx] = __float2bfloat16(r);
                    }
                }
}

// enc1: 1->64 ch, K=4, s=2, relu, out bf16. Cheap direct fp32.
__global__ __launch_bounds__(256) void enc1_k(
    const float* __restrict__ x, const float* __restrict__ w,
    const float* __restrict__ bias, bf16* __restrict__ out)
{
    __shared__ float sIn[260];
    const int tid = threadIdx.x;
    const int b   = blockIdx.y;
    const int l0  = blockIdx.x * 128;
    const float* xb = x + (size_t)b * 4096;
    for (int t = tid; t < 258; t += 256) {
        int g = 2 * l0 - 1 + t;
        sIn[t] = (g >= 0 && g < 4096) ? xb[g] : 0.f;
    }
    __syncthreads();
    const int dl = tid & 127;
    const int cg = tid >> 7;          // wave-uniform
    float xv[4];
#pragma unroll
    for (int k = 0; k < 4; ++k) xv[k] = sIn[2 * dl + k];
    bf16* ob = out + (size_t)b * 64 * 2048 + l0 + dl;
#pragma unroll
    for (int j = 0; j < 32; ++j) {
        int co = cg * 32 + j;
        float a = bias[co];
#pragma unroll
        for (int k = 0; k < 4; ++k) a = fmaf(xv[k], w[co * 4 + k], a);
        a = fmaxf(a, 0.f);
        ob[(size_t)co * 2048] = __float2bfloat16(a);
    }
}

// Final convT: 64->1 ch, x2 upsample, fp32 out.
__global__ __launch_bounds__(256) void ct2_k(
    const bf16* __restrict__ in, const float* __restrict__ w,
    const float* __restrict__ bias, float* __restrict__ out)
{
    __shared__ bf16 sX[64 * 260];
    __shared__ float sW[256];
    const int tid = threadIdx.x;
    const int b   = blockIdx.y;
    const int m0  = blockIdx.x * 256;
    const bf16* inb = in + (size_t)b * 64 * 2048;
    if (tid < 256) sW[tid] = w[tid];
    for (int i = tid; i < 64 * 258; i += 256) {
        int ci = i / 258, t = i - ci * 258;
        int g = m0 - 1 + t;
        sX[ci * 260 + t] = (g >= 0 && g < 2048) ? inb[(size_t)ci * 2048 + g]
                                                : __float2bfloat16(0.f);
    }
    __syncthreads();
    float e = bias[0], o = bias[0];
    for (int ci = 0; ci < 64; ++ci) {
        float xm1 = __bfloat162float(sX[ci * 260 + tid]);
        float x0  = __bfloat162float(sX[ci * 260 + tid + 1]);
        float xp1 = __bfloat162float(sX[ci * 260 + tid + 2]);
        e = fmaf(x0,  sW[ci * 4 + 1], fmaf(xm1, sW[ci * 4 + 3], e));
        o = fmaf(xp1, sW[ci * 4 + 0], fmaf(x0,  sW[ci * 4 + 2], o));
    }
    int m = m0 + tid;
    out[(size_t)b * 4096 + 2 * m]     = e;
    out[(size_t)b * 4096 + 2 * m + 1] = o;
}

// Weight transform: fp32 conv weights -> bf16 [tap][co][ci] matrices.
__global__ __launch_bounds__(256) void wx_k(
    const float* ew2, const float* ew3, const float* er1a, const float* er1b,
    const float* er2a, const float* er2b, const float* pvw, const float* dw1,
    const float* dr1a, const float* dr1b, const float* dr2a, const float* dr2b,
    const float* ct1w, bf16* wb)
{
    const int job = blockIdx.x;
    bf16* dst = wb + (size_t)job * 65536;
    const float* src; int CO, CI, K;
    switch (job) {
        case 0:  src = ew2;  CO = 128; CI = 64;  K = 4; break;
        case 1:  src = ew3;  CO = 128; CI = 128; K = 3; break;
        case 2:  src = er1a; CO = 64;  CI = 128; K = 3; break;
        case 3:  src = er1b; CO = 128; CI = 64;  K = 1; break;
        case 4:  src = er2a; CO = 64;  CI = 128; K = 3; break;
        case 5:  src = er2b; CO = 128; CI = 64;  K = 1; break;
        case 6:  src = pvw;  CO = 64;  CI = 128; K = 1; break;
        case 7:  src = dw1;  CO = 128; CI = 64;  K = 3; break;
        case 8:  src = dr1a; CO = 64;  CI = 128; K = 3; break;
        case 9:  src = dr1b; CO = 128; CI = 64;  K = 1; break;
        case 10: src = dr2a; CO = 64;  CI = 128; K = 3; break;
        case 11: src = dr2b; CO = 128; CI = 64;  K = 1; break;
        default: src = ct1w; CO = 64;  CI = 128; K = 4; break;
    }
    const int tot = CO * CI * K;
    for (int i = blockIdx.y * 256 + threadIdx.x; i < tot; i += gridDim.y * 256) {
        if (job < 12) {
            int k = i / (CO * CI); int r = i - k * CO * CI;
            int co = r / CI; int ci = r - co * CI;
            dst[i] = __float2bfloat16(src[((size_t)co * CI + ci) * K + k]);
        } else {
            // convT1 w (128ci,64co,4) -> [We0=w3, We1=w1, Wo0=w2, Wo1=w0][co][ci]
            const int TAP[4] = {3, 1, 2, 0};
            int g = i / (64 * 128); int r = i - g * 64 * 128;
            int co = r / 128; int ci = r - co * 128;
            dst[i] = __float2bfloat16(src[((size_t)ci * 64 + co) * 4 + TAP[g]]);
        }
    }
}

// codebook squared norms
__global__ __launch_bounds__(256) void cbnorm_k(const float* __restrict__ cb,
                                                float* __restrict__ sc)
{
    int k = blockIdx.x * 256 + threadIdx.x;
    if (k < 512) {
        float s = 0.f;
        const float* c = cb + (size_t)k * 64;
#pragma unroll
        for (int d = 0; d < 64; ++d) s = fmaf(c[d], c[d], s);
        sc[k] = s;
    }
}

// VQ: fp32 argmin over 512 codes; writes q as bf16 NCW, counts, loss-sum.
__global__ __launch_bounds__(256) void vq_k(
    const float* __restrict__ z, const float* __restrict__ cb,
    const float* __restrict__ sc, bf16* __restrict__ qbf,
    float* __restrict__ counts, float* __restrict__ loss_sum)
{
    __shared__ float hcnt[512];
    __shared__ float wsum[4];
    const int tid = threadIdx.x;
    hcnt[tid] = 0.f; hcnt[tid + 256] = 0.f;

    const int n = blockIdx.x * 256 + tid;
    const int b = n >> 10;
    const int l = n & 1023;
    const float* zb = z + (size_t)b * 65536 + l;
    float f[64];
#pragma unroll
    for (int d = 0; d < 64; ++d) f[d] = zb[(size_t)d * 1024];
    float sf = 0.f;
#pragma unroll
    for (int d = 0; d < 64; ++d) sf = fmaf(f[d], f[d], sf);

    float best = 3.4e38f; int bk = 0;
    for (int k = 0; k < 512; ++k) {
        const float* ck = cb + (size_t)k * 64;
        float dot = 0.f;
#pragma unroll
        for (int d = 0; d < 64; ++d) dot = fmaf(f[d], ck[d], dot);
        float dist = sf - 2.f * dot + sc[k];
        if (dist < best) { best = dist; bk = k; }
    }
    __syncthreads();
    atomicAdd(&hcnt[bk], 1.f);

    float lsum = 0.f;
    const float* cbk = cb + (size_t)bk * 64;
    bf16* qb = qbf + (size_t)b * 65536 + l;
#pragma unroll
    for (int d = 0; d < 64; ++d) {
        float qv = cbk[d];
        qb[(size_t)d * 1024] = __float2bfloat16(qv);
        float df = qv - f[d];
        lsum = fmaf(df, df, lsum);
    }
#pragma unroll
    for (int off = 32; off > 0; off >>= 1) lsum += __shfl_down(lsum, off, 64);
    const int lane = tid & 63, wid = tid >> 6;
    if (lane == 0) wsum[wid] = lsum;
    __syncthreads();
    if (tid == 0) atomicAdd(loss_sum, wsum[0] + wsum[1] + wsum[2] + wsum[3]);
    float c0 = hcnt[tid];       if (c0 != 0.f) atomicAdd(&counts[tid], c0);
    float c1 = hcnt[tid + 256]; if (c1 != 0.f) atomicAdd(&counts[tid + 256], c1);
}

__global__ __launch_bounds__(512) void finalize_k(
    const float* __restrict__ counts, const float* __restrict__ loss_sum,
    float* __restrict__ d_out, int out_size)
{
    __shared__ float ws2[8];
    const int tid = threadIdx.x;
    float p = counts[tid] * (1.f / 131072.f);
    float e = p * logf(p + 1e-10f);
#pragma unroll
    for (int off = 32; off > 0; off >>= 1) e += __shfl_down(e, off, 64);
    const int lane = tid & 63, wid = tid >> 6;
    if (lane == 0) ws2[wid] = e;
    __syncthreads();
    if (tid == 0) {
        float s = 0.f;
        for (int i = 0; i < 8; ++i) s += ws2[i];
        d_out[0] = 1.25f * loss_sum[0] * (1.f / 8388608.f);  // (1+BETA)*mean
        d_out[out_size - 1] = expf(-s);
    }
}

extern "C" void kernel_launch(void* const* d_in, const int* in_sizes, int n_in,
                              void* d_out, int out_size, void* d_ws, size_t ws_size,
                              hipStream_t stream)
{
    const float* x        = (const float*)d_in[0];
    const float* enc_w1   = (const float*)d_in[1];
    const float* enc_b1   = (const float*)d_in[2];
    const float* enc_w2   = (const float*)d_in[3];
    const float* enc_b2   = (const float*)d_in[4];
    const float* enc_w3   = (const float*)d_in[5];
    const float* enc_b3   = (const float*)d_in[6];
    const float* enc_r1a  = (const float*)d_in[7];
    const float* enc_r1b  = (const float*)d_in[8];
    const float* enc_r2a  = (const float*)d_in[9];
    const float* enc_r2b  = (const float*)d_in[10];
    const float* pre_vq_w = (const float*)d_in[11];
    const float* pre_vq_b = (const float*)d_in[12];
    const float* cb       = (const float*)d_in[13];
    const float* dec_w1   = (const float*)d_in[14];
    const float* dec_b1   = (const float*)d_in[15];
    const float* dec_r1a  = (const float*)d_in[16];
    const float* dec_r1b  = (const float*)d_in[17];
    const float* dec_r2a  = (const float*)d_in[18];
    const float* dec_r2b  = (const float*)d_in[19];
    const float* ct1_w    = (const float*)d_in[20];
    const float* ct1_b    = (const float*)d_in[21];
    const float* ct2_w    = (const float*)d_in[22];
    const float* ct2_b    = (const float*)d_in[23];
    float* out = (float*)d_out;

    char* base = (char*)d_ws;
    bf16*  wb   = (bf16*)base;                          // 13 slots x 64K bf16
    bf16*  Abf  = (bf16*)(base + ((size_t)2  << 20));   // 16.8M bf16
    bf16*  Bbf  = (bf16*)(base + ((size_t)36 << 20));   // 16.8M bf16
    bf16*  Qbf  = (bf16*)(base + ((size_t)70 << 20));   // 8.4M bf16
    float* Zf   = (float*)(base + ((size_t)88 << 20));  // 8.4M f32
    float* sc   = (float*)(base + ((size_t)122 << 20)); // 512
    float* cnt  = sc + 512;                             // 512
    float* lsum = sc + 1024;                            // 1

    hipMemsetAsync(cnt, 0, 513 * sizeof(float), stream);

    dim3 blk(256);
    dim3 g16(16, 128);

    wx_k<<<dim3(13, 8), blk, 0, stream>>>(enc_w2, enc_w3, enc_r1a, enc_r1b,
        enc_r2a, enc_r2b, pre_vq_w, dec_w1, dec_r1a, dec_r1b, dec_r2a, dec_r2b,
        ct1_w, wb);

    enc1_k<<<g16, blk, 0, stream>>>(x, enc_w1, enc_b1, Abf);
    gconv_k<64,128,4,M_S2,false,true ,false,true ,false><<<g16, blk, 0, stream>>>(
        Abf, wb + 0 * 65536, enc_b2, Bbf, 2048, 1024);
    gconv_k<128,128,3,M_S1,false,false,false,true ,false><<<g16, blk, 0, stream>>>(
        Bbf, wb + 1 * 65536, enc_b3, Abf, 1024, 1024);
    gconv_k<128,64,3,M_S1,true ,false,false,false,false><<<g16, blk, 0, stream>>>(
        Abf, wb + 2 * 65536, nullptr, Bbf, 1024, 1024);
    gconv_k<64,128,1,M_S1,true ,false,true ,false,false><<<g16, blk, 0, stream>>>(
        Bbf, wb + 3 * 65536, nullptr, Abf, 1024, 1024);
    gconv_k<128,64,3,M_S1,true ,false,false,false,false><<<g16, blk, 0, stream>>>(
        Abf, wb + 4 * 65536, nullptr, Bbf, 1024, 1024);
    gconv_k<64,128,1,M_S1,true ,false,true ,false,false><<<g16, blk, 0, stream>>>(
        Bbf, wb + 5 * 65536, nullptr, Abf, 1024, 1024);
    gconv_k<128,64,1,M_S1,true ,false,false,true ,true ><<<g16, blk, 0, stream>>>(
        Abf, wb + 6 * 65536, pre_vq_b, Zf, 1024, 1024);

    cbnorm_k<<<2, 256, 0, stream>>>(cb, sc);
    vq_k<<<512, 256, 0, stream>>>(Zf, cb, sc, Qbf, cnt, lsum);

    gconv_k<64,128,3,M_S1,false,false,false,true ,false><<<g16, blk, 0, stream>>>(
        Qbf, wb + 7 * 65536, dec_b1, Abf, 1024, 1024);
    gconv_k<128,64,3,M_S1,true ,false,false,false,false><<<g16, blk, 0, stream>>>(
        Abf, wb + 8 * 65536, nullptr, Bbf, 1024, 1024);
    gconv_k<64,128,1,M_S1,true ,false,true ,false,false><<<g16, blk, 0, stream>>>(
        Bbf, wb + 9 * 65536, nullptr, Abf, 1024, 1024);
    gconv_k<128,64,3,M_S1,true ,false,false,false,false><<<g16, blk, 0, stream>>>(
        Abf, wb + 10 * 65536, nullptr, Bbf, 1024, 1024);
    gconv_k<64,128,1,M_S1,true ,false,true ,false,false><<<g16, blk, 0, stream>>>(
        Bbf, wb + 11 * 65536, nullptr, Abf, 1024, 1024);
    gconv_k<128,64,2,M_CT,true ,true ,false,true ,false><<<g16, blk, 0, stream>>>(
        Abf, wb + 12 * 65536, ct1_b, Bbf, 1024, 2048);

    ct2_k<<<dim3(8, 128), blk, 0, stream>>>(Bbf, ct2_w, ct2_b, out + 1);
    finalize_k<<<1, 512, 0, stream>>>(cnt, lsum, out, out_size);
}

// Round 5
// 470.513 us; speedup vs baseline: 5.0600x; 1.6736x over previous
//
#include <hip/hip_runtime.h>
#include <hip/hip_bf16.h>
#include <math.h>

using bf16 = __hip_bfloat16;
typedef __attribute__((ext_vector_type(4))) float f32x4;
typedef __attribute__((ext_vector_type(8))) short s16x8;

#define MFMA16(a,b,c) __builtin_amdgcn_mfma_f32_16x16x32_bf16((a),(b),(c),0,0,0)

// ---------------------------------------------------------------------------
// VQ-VAE forward. B=128, L=4096, H=128, RH=64, D=64, K=512.
// Activations channel-last (b, l, c) bf16; z kept fp32 for VQ argmin fidelity.
// Convs: bf16 MFMA GEMM-convs. VQ: split-bf16 MFMA distance GEMM (fp32-grade).
// ---------------------------------------------------------------------------

__device__ inline float bf2f(unsigned short u) {
    union { float f; unsigned v; } c; c.v = ((unsigned)u) << 16; return c.f;
}
__device__ inline unsigned short bfbits(float f) {
    union { bf16 h; unsigned short u; } c; c.h = __float2bfloat16(f); return c.u;
}
__device__ inline s16x8 relu8(s16x8 v) {
#pragma unroll
    for (int j = 0; j < 8; ++j)
        v[j] = (short)(((unsigned short)v[j] & 0x8000u) ? 0 : (unsigned short)v[j]);
    return v;
}

enum { M_S1 = 0, M_S2 = 1, M_CT = 2 };

// GEMM-conv, channel-last. in (b,Lin,CIN) bf16, out (b,Lout,COUT) bf16/f32.
template<int CIN, int COUT, int NTAP, int MODE, bool RELU_IN, bool RELU_OUT,
         bool ACC, bool HAS_BIAS, bool OUT_F32>
__global__ __launch_bounds__(256) void gconv_k(
    const bf16* __restrict__ in, const bf16* __restrict__ wt,
    const float* __restrict__ bias, void* __restrict__ outv,
    int Lin, int Lout)
{
    constexpr int T  = (MODE == M_S2) ? 132 : ((MODE == M_CT) ? 66 : (NTAP == 3 ? 66 : 64));
    constexpr int NG = (MODE == M_CT) ? 2 : 1;
    constexpr int WL = (COUT == 128) ? 4 : 2;
    constexpr int KS = CIN / 32;
    constexpr int SOFF = (MODE == M_CT || NTAP == 3) ? -1 : 0;
    __shared__ bf16 sX[T * CIN];

    const int tid = threadIdx.x;
    const int b   = blockIdx.y;
    const int l0  = blockIdx.x * 64;
    const bf16* inb = in + (size_t)b * Lin * CIN;

    constexpr int CPR = CIN / 8;
    for (int i = tid; i < T * CPR; i += 256) {
        int t  = i / CPR;
        int c0 = (i - t * CPR) * 8;
        int g;
        if (MODE == M_S2) g = (t < 66) ? 2 * (l0 + t) : 2 * (l0 + t - 66) - 1;
        else              g = l0 + t + SOFF;
        s16x8 v = {};
        if (g >= 0 && g < Lin) v = *(const s16x8*)(inb + (size_t)g * CIN + c0);
        if (RELU_IN) v = relu8(v);
        int byte = ((t * CIN + c0) << 1) ^ ((t & 7) << 4);
        *(s16x8*)((char*)sX + byte) = v;
    }
    __syncthreads();

    const int lane = tid & 63;
    const int wid  = __builtin_amdgcn_readfirstlane(tid >> 6);
    const int co0  = (COUT == 128) ? wid * 32 : (wid & 1) * 32;
    const int lw0  = (COUT == 128) ? 0 : (wid >> 1) * 32;
    const int lr   = lane & 15;
    const int kg   = lane >> 4;

    f32x4 acc[NG][2][WL];
#pragma unroll
    for (int g = 0; g < NG; ++g)
#pragma unroll
        for (int cf = 0; cf < 2; ++cf)
#pragma unroll
            for (int lf = 0; lf < WL; ++lf)
                acc[g][cf][lf] = (f32x4){0.f, 0.f, 0.f, 0.f};

#pragma unroll
    for (int g = 0; g < NG; ++g) {
#pragma unroll
        for (int k = 0; k < NTAP; ++k) {
            int roff;
            if (MODE == M_S1)      roff = k;
            else if (MODE == M_S2) roff = (k == 0) ? 66 : (k == 1) ? 0 : (k == 2) ? 67 : 1;
            else                   roff = g + k;
            const bf16* Ab = wt + (size_t)(g * NTAP + k) * COUT * CIN;
#pragma unroll
            for (int ks = 0; ks < KS; ++ks) {
                s16x8 af[2];
#pragma unroll
                for (int cf = 0; cf < 2; ++cf)
                    af[cf] = *(const s16x8*)(Ab + (co0 + cf * 16 + lr) * CIN + ks * 32 + kg * 8);
                s16x8 bfr[WL];
#pragma unroll
                for (int lf = 0; lf < WL; ++lf) {
                    int t = roff + lw0 + lf * 16 + lr;
                    int byte = ((t * CIN + ks * 32 + kg * 8) << 1) ^ ((t & 7) << 4);
                    bfr[lf] = *(const s16x8*)((const char*)sX + byte);
                }
#pragma unroll
                for (int cf = 0; cf < 2; ++cf)
#pragma unroll
                    for (int lf = 0; lf < WL; ++lf)
                        acc[g][cf][lf] = MFMA16(af[cf], bfr[lf], acc[g][cf][lf]);
            }
        }
    }

#pragma unroll
    for (int g = 0; g < NG; ++g)
#pragma unroll
        for (int cf = 0; cf < 2; ++cf)
#pragma unroll
            for (int lf = 0; lf < WL; ++lf) {
                int cb0  = co0 + cf * 16 + kg * 4;
                int lcol = lw0 + lf * 16 + lr;
                int gcol = (MODE == M_CT) ? (2 * (l0 + lcol) + g) : (l0 + lcol);
                float r[4];
#pragma unroll
                for (int j = 0; j < 4; ++j) {
                    r[j] = acc[g][cf][lf][j];
                    if (HAS_BIAS) r[j] += bias[cb0 + j];
                }
                if (OUT_F32) {
                    float* pf = (float*)outv + ((size_t)b * Lout + gcol) * COUT + cb0;
                    *(float4*)pf = make_float4(r[0], r[1], r[2], r[3]);
                } else {
                    bf16* po = (bf16*)outv + ((size_t)b * Lout + gcol) * COUT + cb0;
                    if (ACC) {
                        uint2 old = *(const uint2*)po;
                        r[0] += bf2f((unsigned short)(old.x & 0xffff));
                        r[1] += bf2f((unsigned short)(old.x >> 16));
                        r[2] += bf2f((unsigned short)(old.y & 0xffff));
                        r[3] += bf2f((unsigned short)(old.y >> 16));
                    }
                    if (RELU_OUT)
#pragma unroll
                        for (int j = 0; j < 4; ++j) r[j] = fmaxf(r[j], 0.f);
                    uint2 pk;
                    pk.x = (unsigned)bfbits(r[0]) | ((unsigned)bfbits(r[1]) << 16);
                    pk.y = (unsigned)bfbits(r[2]) | ((unsigned)bfbits(r[3]) << 16);
                    *(uint2*)po = pk;
                }
            }
}

// enc1: 1->64 ch, K=4, s=2, relu; fp32 in, bf16 (b,l,c) out.
__global__ __launch_bounds__(256) void enc1_k(
    const float* __restrict__ x, const float* __restrict__ w,
    const float* __restrict__ bias, bf16* __restrict__ out)
{
    const int tid = threadIdx.x;
    const int b   = blockIdx.y;
    const int l   = blockIdx.x * 256 + tid;
    const float* xb = x + (size_t)b * 4096;
    float xv[4];
#pragma unroll
    for (int k = 0; k < 4; ++k) {
        int g = 2 * l - 1 + k;
        xv[k] = (g >= 0 && g < 4096) ? xb[g] : 0.f;
    }
    bf16* ob = out + ((size_t)b * 2048 + l) * 64;
#pragma unroll
    for (int c0 = 0; c0 < 64; c0 += 8) {
        union { unsigned short u[8]; s16x8 v; } pk;
#pragma unroll
        for (int j = 0; j < 8; ++j) {
            int co = c0 + j;
            float a = bias[co];
#pragma unroll
            for (int k = 0; k < 4; ++k) a = fmaf(xv[k], w[co * 4 + k], a);
            pk.u[j] = bfbits(fmaxf(a, 0.f));
        }
        *(s16x8*)(ob + c0) = pk.v;
    }
}

// Final convT: 64->1 ch, x2 upsample; (b,l,c) bf16 in, fp32 out.
__global__ __launch_bounds__(256) void ct2_k(
    const bf16* __restrict__ in, const float* __restrict__ w,
    const float* __restrict__ bias, float* __restrict__ out)
{
    __shared__ bf16 sX[258 * 64];
    const int tid = threadIdx.x;
    const int b   = blockIdx.y;
    const int m0  = blockIdx.x * 256;
    const bf16* inb = in + (size_t)b * 2048 * 64;
    for (int i = tid; i < 258 * 8; i += 256) {
        int t = i >> 3, c0 = (i & 7) * 8;
        int g = m0 - 1 + t;
        s16x8 v = {};
        if (g >= 0 && g < 2048) v = *(const s16x8*)(inb + (size_t)g * 64 + c0);
        int byte = ((t * 64 + c0) << 1) ^ ((t & 7) << 4);
        *(s16x8*)((char*)sX + byte) = v;
    }
    __syncthreads();
    float e = bias[0], o = bias[0];
#pragma unroll
    for (int c0 = 0; c0 < 64; c0 += 8) {
        int t0 = tid, t1 = tid + 1, t2 = tid + 2;
        s16x8 vm1 = *(const s16x8*)((char*)sX + (((t0 * 64 + c0) << 1) ^ ((t0 & 7) << 4)));
        s16x8 v0  = *(const s16x8*)((char*)sX + (((t1 * 64 + c0) << 1) ^ ((t1 & 7) << 4)));
        s16x8 vp1 = *(const s16x8*)((char*)sX + (((t2 * 64 + c0) << 1) ^ ((t2 & 7) << 4)));
#pragma unroll
        for (int j = 0; j < 8; ++j) {
            int ci = c0 + j;
            float xm1 = bf2f((unsigned short)vm1[j]);
            float x0  = bf2f((unsigned short)v0[j]);
            float xp1 = bf2f((unsigned short)vp1[j]);
            e = fmaf(x0,  w[ci * 4 + 1], fmaf(xm1, w[ci * 4 + 3], e));
            o = fmaf(xp1, w[ci * 4 + 0], fmaf(x0,  w[ci * 4 + 2], o));
        }
    }
    int m = m0 + tid;
    out[(size_t)b * 4096 + 2 * m]     = e;
    out[(size_t)b * 4096 + 2 * m + 1] = o;
}

// Weight transform: fp32 conv weights -> bf16 [tap][co][ci] matrices.
__global__ __launch_bounds__(256) void wx_k(
    const float* ew2, const float* ew3, const float* er1a, const float* er1b,
    const float* er2a, const float* er2b, const float* pvw, const float* dw1,
    const float* dr1a, const float* dr1b, const float* dr2a, const float* dr2b,
    const float* ct1w, bf16* wb)
{
    const int job = blockIdx.x;
    bf16* dst = wb + (size_t)job * 65536;
    const float* src; int CO, CI, K;
    switch (job) {
        case 0:  src = ew2;  CO = 128; CI = 64;  K = 4; break;
        case 1:  src = ew3;  CO = 128; CI = 128; K = 3; break;
        case 2:  src = er1a; CO = 64;  CI = 128; K = 3; break;
        case 3:  src = er1b; CO = 128; CI = 64;  K = 1; break;
        case 4:  src = er2a; CO = 64;  CI = 128; K = 3; break;
        case 5:  src = er2b; CO = 128; CI = 64;  K = 1; break;
        case 6:  src = pvw;  CO = 64;  CI = 128; K = 1; break;
        case 7:  src = dw1;  CO = 128; CI = 64;  K = 3; break;
        case 8:  src = dr1a; CO = 64;  CI = 128; K = 3; break;
        case 9:  src = dr1b; CO = 128; CI = 64;  K = 1; break;
        case 10: src = dr2a; CO = 64;  CI = 128; K = 3; break;
        case 11: src = dr2b; CO = 128; CI = 64;  K = 1; break;
        default: src = ct1w; CO = 64;  CI = 128; K = 4; break;
    }
    const int tot = CO * CI * K;
    for (int i = blockIdx.y * 256 + threadIdx.x; i < tot; i += gridDim.y * 256) {
        if (job < 12) {
            int k = i / (CO * CI); int r = i - k * CO * CI;
            int co = r / CI; int ci = r - co * CI;
            dst[i] = __float2bfloat16(src[((size_t)co * CI + ci) * K + k]);
        } else {
            const int TAP[4] = {3, 1, 2, 0};   // [We0,We1,Wo0,Wo1]
            int g = i / (64 * 128); int r = i - g * 64 * 128;
            int co = r / 128; int ci = r - co * 128;
            dst[i] = __float2bfloat16(src[((size_t)ci * 64 + co) * 4 + TAP[g]]);
        }
    }
}

// codebook prep: fp32 norms + hi/lo bf16 split
__global__ __launch_bounds__(256) void cbprep_k(
    const float* __restrict__ cb, bf16* __restrict__ cbh, bf16* __restrict__ cbl,
    float* __restrict__ sc)
{
    int k = blockIdx.x * 256 + threadIdx.x;   // grid 2
    const float* c = cb + (size_t)k * 64;
    float s = 0.f;
#pragma unroll
    for (int d = 0; d < 64; ++d) s = fmaf(c[d], c[d], s);
    sc[k] = s;
#pragma unroll
    for (int c0 = 0; c0 < 64; c0 += 8) {
        union { unsigned short u[8]; s16x8 v; } ph, pl;
#pragma unroll
        for (int j = 0; j < 8; ++j) {
            float v = c[c0 + j];
            unsigned short h = bfbits(v);
            ph.u[j] = h;
            pl.u[j] = bfbits(v - bf2f(h));
        }
        *(s16x8*)(cbh + (size_t)k * 64 + c0) = ph.v;
        *(s16x8*)(cbl + (size_t)k * 64 + c0) = pl.v;
    }
}

// VQ: split-bf16 MFMA distance GEMM (fp32-grade argmin).
// z fp32 (b,l,64) -> q bf16 (b,l,64), counts, loss.
__global__ __launch_bounds__(256) void vq_k(
    const float* __restrict__ z, const float* __restrict__ cbf,
    const bf16* __restrict__ cbh, const bf16* __restrict__ cbl,
    const float* __restrict__ sc, bf16* __restrict__ q,
    float* __restrict__ counts, float* __restrict__ loss_sum)
{
    __shared__ float sSC[512];
    __shared__ float sHist[512];
    __shared__ int   sBK[256];
    __shared__ float sWS[4];
    const int tid = threadIdx.x;
    sSC[tid] = sc[tid]; sSC[tid + 256] = sc[tid + 256];
    sHist[tid] = 0.f;   sHist[tid + 256] = 0.f;

    const int lane = tid & 63, wid = tid >> 6;
    const int lr = lane & 15, kg = lane >> 4;
    const int n0 = blockIdx.x * 256 + wid * 64;
    const f32x4 zf4 = {0.f, 0.f, 0.f, 0.f};

    // load 4x16 z rows, split into hi/lo bf16 fragments
    s16x8 bh[4][2], bl[4][2];
#pragma unroll
    for (int lf = 0; lf < 4; ++lf)
#pragma unroll
        for (int ks = 0; ks < 2; ++ks) {
            const float* zp = z + (size_t)(n0 + lf * 16 + lr) * 64 + ks * 32 + kg * 8;
            float4 v0 = *(const float4*)zp;
            float4 v1 = *(const float4*)(zp + 4);
            float v[8] = {v0.x, v0.y, v0.z, v0.w, v1.x, v1.y, v1.z, v1.w};
            union { unsigned short u[8]; s16x8 s; } ph, pl;
#pragma unroll
            for (int j = 0; j < 8; ++j) {
                unsigned short h = bfbits(v[j]);
                ph.u[j] = h;
                pl.u[j] = bfbits(v[j] - bf2f(h));
            }
            bh[lf][ks] = ph.s; bl[lf][ks] = pl.s;
        }
    __syncthreads();

    float bestd[4] = {3.4e38f, 3.4e38f, 3.4e38f, 3.4e38f};
    int   bestk[4] = {0, 0, 0, 0};
#pragma unroll 2
    for (int cf = 0; cf < 32; ++cf) {
        int code = cf * 16 + lr;
        const bf16* ph = cbh + code * 64 + kg * 8;
        const bf16* pl = cbl + code * 64 + kg * 8;
        s16x8 ah0 = *(const s16x8*)ph;
        s16x8 ah1 = *(const s16x8*)(ph + 32);
        s16x8 al0 = *(const s16x8*)pl;
        s16x8 al1 = *(const s16x8*)(pl + 32);
        float s0 = sSC[cf * 16 + kg * 4 + 0];
        float s1 = sSC[cf * 16 + kg * 4 + 1];
        float s2 = sSC[cf * 16 + kg * 4 + 2];
        float s3 = sSC[cf * 16 + kg * 4 + 3];
        int kb = cf * 16 + kg * 4;
#pragma unroll
        for (int lf = 0; lf < 4; ++lf) {
            f32x4 acc = MFMA16(ah0, bh[lf][0], zf4);
            acc = MFMA16(ah1, bh[lf][1], acc);
            acc = MFMA16(al0, bh[lf][0], acc);   // c_lo . z_hi
            acc = MFMA16(al1, bh[lf][1], acc);
            acc = MFMA16(ah0, bl[lf][0], acc);   // c_hi . z_lo
            acc = MFMA16(ah1, bl[lf][1], acc);
            float d0 = fmaf(acc[0], -2.f, s0);
            float d1 = fmaf(acc[1], -2.f, s1);
            float d2 = fmaf(acc[2], -2.f, s2);
            float d3 = fmaf(acc[3], -2.f, s3);
            if (d0 < bestd[lf]) { bestd[lf] = d0; bestk[lf] = kb; }
            if (d1 < bestd[lf]) { bestd[lf] = d1; bestk[lf] = kb + 1; }
            if (d2 < bestd[lf]) { bestd[lf] = d2; bestk[lf] = kb + 2; }
            if (d3 < bestd[lf]) { bestd[lf] = d3; bestk[lf] = kb + 3; }
        }
    }
#pragma unroll
    for (int lf = 0; lf < 4; ++lf) {
#pragma unroll
        for (int off = 16; off <= 32; off <<= 1) {
            float od = __shfl_xor(bestd[lf], off, 64);
            int   ok = __shfl_xor(bestk[lf], off, 64);
            if (od < bestd[lf] || (od == bestd[lf] && ok < bestk[lf])) {
                bestd[lf] = od; bestk[lf] = ok;
            }
        }
        if (kg == 0) sBK[wid * 64 + lf * 16 + lr] = bestk[lf];
    }
    __syncthreads();

    // phase 2: q write (bf16), loss (fp32 q,z), histogram
    const int n = blockIdx.x * 256 + tid;
    const int k = sBK[tid];
    atomicAdd(&sHist[k], 1.f);
    float lsum = 0.f;
    const float* qp = cbf + (size_t)k * 64;
    const float* zp = z + (size_t)n * 64;
#pragma unroll
    for (int c0 = 0; c0 < 64; c0 += 8) {
        float4 q0 = *(const float4*)(qp + c0);
        float4 q1 = *(const float4*)(qp + c0 + 4);
        float4 z0 = *(const float4*)(zp + c0);
        float4 z1 = *(const float4*)(zp + c0 + 4);
        float qv[8] = {q0.x, q0.y, q0.z, q0.w, q1.x, q1.y, q1.z, q1.w};
        float zv[8] = {z0.x, z0.y, z0.z, z0.w, z1.x, z1.y, z1.z, z1.w};
        union { unsigned short u[8]; s16x8 v; } pk;
#pragma unroll
        for (int j = 0; j < 8; ++j) {
            float d = qv[j] - zv[j];
            lsum = fmaf(d, d, lsum);
            pk.u[j] = bfbits(qv[j]);
        }
        *(s16x8*)(q + (size_t)n * 64 + c0) = pk.v;
    }
#pragma unroll
    for (int off = 32; off > 0; off >>= 1) lsum += __shfl_down(lsum, off, 64);
    if ((tid & 63) == 0) sWS[tid >> 6] = lsum;
    __syncthreads();
    if (tid == 0) atomicAdd(loss_sum, sWS[0] + sWS[1] + sWS[2] + sWS[3]);
    float c0v = sHist[tid];       if (c0v != 0.f) atomicAdd(&counts[tid], c0v);
    float c1v = sHist[tid + 256]; if (c1v != 0.f) atomicAdd(&counts[tid + 256], c1v);
}

__global__ __launch_bounds__(512) void finalize_k(
    const float* __restrict__ counts, const float* __restrict__ loss_sum,
    float* __restrict__ d_out, int out_size)
{
    __shared__ float ws2[8];
    const int tid = threadIdx.x;
    float p = counts[tid] * (1.f / 131072.f);
    float e = p * logf(p + 1e-10f);
#pragma unroll
    for (int off = 32; off > 0; off >>= 1) e += __shfl_down(e, off, 64);
    const int lane = tid & 63, wid = tid >> 6;
    if (lane == 0) ws2[wid] = e;
    __syncthreads();
    if (tid == 0) {
        float s = 0.f;
        for (int i = 0; i < 8; ++i) s += ws2[i];
        d_out[0] = 1.25f * loss_sum[0] * (1.f / 8388608.f);  // (1+BETA)*mean
        d_out[out_size - 1] = expf(-s);
    }
}

extern "C" void kernel_launch(void* const* d_in, const int* in_sizes, int n_in,
                              void* d_out, int out_size, void* d_ws, size_t ws_size,
                              hipStream_t stream)
{
    const float* x        = (const float*)d_in[0];
    const float* enc_w1   = (const float*)d_in[1];
    const float* enc_b1   = (const float*)d_in[2];
    const float* enc_b2   = (const float*)d_in[4];
    const float* enc_b3   = (const float*)d_in[6];
    const float* pre_vq_b = (const float*)d_in[12];
    const float* cb       = (const float*)d_in[13];
    const float* dec_b1   = (const float*)d_in[15];
    const float* ct1_b    = (const float*)d_in[21];
    const float* ct2_w    = (const float*)d_in[22];
    const float* ct2_b    = (const float*)d_in[23];
    float* out = (float*)d_out;

    char* base = (char*)d_ws;
    bf16*  wb   = (bf16*)base;                            // 13 x 64K bf16 = 1.7MB
    bf16*  Abf  = (bf16*)(base + ((size_t)2   << 20));    // 33.5MB
    bf16*  Bbf  = (bf16*)(base + ((size_t)40  << 20));    // 33.5MB
    float* Zf   = (float*)(base + ((size_t)78  << 20));   // 33.5MB fp32
    bf16*  Qbf  = (bf16*)(base + ((size_t)112 << 20));    // 16.7MB
    bf16*  cbh  = (bf16*)(base + ((size_t)130 << 20));    // 64KB
    bf16*  cbl  = (bf16*)(base + ((size_t)130 << 20) + 65536);
    float* sc   = (float*)(base + ((size_t)130 << 20) + 131072);
    float* cnt  = sc + 512;
    float* lsum = cnt + 512;

    hipMemsetAsync(cnt, 0, 513 * sizeof(float), stream);

    dim3 blk(256);
    dim3 g16(16, 128);

    wx_k<<<dim3(13, 8), blk, 0, stream>>>(
        (const float*)d_in[3], (const float*)d_in[5], (const float*)d_in[7],
        (const float*)d_in[8], (const float*)d_in[9], (const float*)d_in[10],
        (const float*)d_in[11], (const float*)d_in[14], (const float*)d_in[16],
        (const float*)d_in[17], (const float*)d_in[18], (const float*)d_in[19],
        (const float*)d_in[20], wb);
    cbprep_k<<<2, blk, 0, stream>>>(cb, cbh, cbl, sc);

    enc1_k<<<dim3(8, 128), blk, 0, stream>>>(x, enc_w1, enc_b1, Abf);
    gconv_k<64,128,4,M_S2,false,true ,false,true ,false><<<g16, blk, 0, stream>>>(
        Abf, wb + 0 * 65536, enc_b2, Bbf, 2048, 1024);
    gconv_k<128,128,3,M_S1,false,false,false,true ,false><<<g16, blk, 0, stream>>>(
        Bbf, wb + 1 * 65536, enc_b3, Abf, 1024, 1024);
    gconv_k<128,64,3,M_S1,true ,false,false,false,false><<<g16, blk, 0, stream>>>(
        Abf, wb + 2 * 65536, nullptr, Bbf, 1024, 1024);
    gconv_k<64,128,1,M_S1,true ,false,true ,false,false><<<g16, blk, 0, stream>>>(
        Bbf, wb + 3 * 65536, nullptr, Abf, 1024, 1024);
    gconv_k<128,64,3,M_S1,true ,false,false,false,false><<<g16, blk, 0, stream>>>(
        Abf, wb + 4 * 65536, nullptr, Bbf, 1024, 1024);
    gconv_k<64,128,1,M_S1,true ,false,true ,false,false><<<g16, blk, 0, stream>>>(
        Bbf, wb + 5 * 65536, nullptr, Abf, 1024, 1024);
    gconv_k<128,64,1,M_S1,true ,false,false,true ,true ><<<g16, blk, 0, stream>>>(
        Abf, wb + 6 * 65536, pre_vq_b, Zf, 1024, 1024);

    vq_k<<<512, blk, 0, stream>>>(Zf, cb, cbh, cbl, sc, Qbf, cnt, lsum);

    gconv_k<64,128,3,M_S1,false,false,false,true ,false><<<g16, blk, 0, stream>>>(
        Qbf, wb + 7 * 65536, dec_b1, Abf, 1024, 1024);
    gconv_k<128,64,3,M_S1,true ,false,false,false,false><<<g16, blk, 0, stream>>>(
        Abf, wb + 8 * 65536, nullptr, Bbf, 1024, 1024);
    gconv_k<64,128,1,M_S1,true ,false,true ,false,false><<<g16, blk, 0, stream>>>(
        Bbf, wb + 9 * 65536, nullptr, Abf, 1024, 1024);
    gconv_k<128,64,3,M_S1,true ,false,false,false,false><<<g16, blk, 0, stream>>>(
        Abf, wb + 10 * 65536, nullptr, Bbf, 1024, 1024);
    gconv_k<64,128,1,M_S1,true ,false,true ,false,false><<<g16, blk, 0, stream>>>(
        Bbf, wb + 11 * 65536, nullptr, Abf, 1024, 1024);
    gconv_k<128,64,2,M_CT,true ,true ,false,true ,false><<<g16, blk, 0, stream>>>(
        Abf, wb + 12 * 65536, ct1_b, Bbf, 1024, 2048);

    ct2_k<<<dim3(8, 128), blk, 0, stream>>>(Bbf, ct2_w, ct2_b, out + 1);
    finalize_k<<<1, 512, 0, stream>>>(cnt, lsum, out, out_size);
}

// Round 6
// 418.052 us; speedup vs baseline: 5.6949x; 1.1255x over previous
//
#include <hip/hip_runtime.h>
#include <hip/hip_bf16.h>
#include <math.h>

using bf16 = __hip_bfloat16;
typedef __attribute__((ext_vector_type(4))) float f32x4;
typedef __attribute__((ext_vector_type(8))) short s16x8;

#define MFMA16(a,b,c) __builtin_amdgcn_mfma_f32_16x16x32_bf16((a),(b),(c),0,0,0)

// ---------------------------------------------------------------------------
// VQ-VAE forward. B=128, L=4096, H=128, RH=64, D=64, K=512.
// Channel-last bf16 activations. Fused res-blocks; fused pre_vq+VQ.
// ---------------------------------------------------------------------------

__device__ inline float bf2f(unsigned short u) {
    union { float f; unsigned v; } c; c.v = ((unsigned)u) << 16; return c.f;
}
__device__ inline unsigned short bfbits(float f) {
    union { bf16 h; unsigned short u; } c; c.h = __float2bfloat16(f); return c.u;
}
__device__ inline s16x8 relu8(s16x8 v) {
#pragma unroll
    for (int j = 0; j < 8; ++j)
        v[j] = (short)(((unsigned short)v[j] & 0x8000u) ? 0 : (unsigned short)v[j]);
    return v;
}

enum { M_S1 = 0, M_S2 = 1, M_CT = 2 };

// Generic GEMM-conv (used for enc2, enc3, dec1, ct1).
template<int CIN, int COUT, int NTAP, int MODE, bool RELU_IN, bool RELU_OUT,
         bool HAS_BIAS>
__global__ __launch_bounds__(256) void gconv_k(
    const bf16* __restrict__ in, const bf16* __restrict__ wt,
    const float* __restrict__ bias, bf16* __restrict__ out,
    int Lin, int Lout)
{
    constexpr int T  = (MODE == M_S2) ? 132 : ((MODE == M_CT) ? 66 : (NTAP == 3 ? 66 : 64));
    constexpr int NG = (MODE == M_CT) ? 2 : 1;
    constexpr int WL = (COUT == 128) ? 4 : 2;
    constexpr int KS = CIN / 32;
    constexpr int SOFF = (MODE == M_CT || NTAP == 3) ? -1 : 0;
    __shared__ bf16 sX[T * CIN];

    const int tid = threadIdx.x;
    const int b   = blockIdx.y;
    const int l0  = blockIdx.x * 64;
    const bf16* inb = in + (size_t)b * Lin * CIN;

    constexpr int CPR = CIN / 8;
    for (int i = tid; i < T * CPR; i += 256) {
        int t  = i / CPR;
        int c0 = (i - t * CPR) * 8;
        int g;
        if (MODE == M_S2) g = (t < 66) ? 2 * (l0 + t) : 2 * (l0 + t - 66) - 1;
        else              g = l0 + t + SOFF;
        s16x8 v = {};
        if (g >= 0 && g < Lin) v = *(const s16x8*)(inb + (size_t)g * CIN + c0);
        if (RELU_IN) v = relu8(v);
        int byte = ((t * CIN + c0) << 1) ^ ((t & 7) << 4);
        *(s16x8*)((char*)sX + byte) = v;
    }
    __syncthreads();

    const int lane = tid & 63;
    const int wid  = __builtin_amdgcn_readfirstlane(tid >> 6);
    const int co0  = (COUT == 128) ? wid * 32 : (wid & 1) * 32;
    const int lw0  = (COUT == 128) ? 0 : (wid >> 1) * 32;
    const int lr   = lane & 15;
    const int kg   = lane >> 4;

    f32x4 acc[NG][2][WL];
#pragma unroll
    for (int g = 0; g < NG; ++g)
#pragma unroll
        for (int cf = 0; cf < 2; ++cf)
#pragma unroll
            for (int lf = 0; lf < WL; ++lf)
                acc[g][cf][lf] = (f32x4){0.f, 0.f, 0.f, 0.f};

#pragma unroll
    for (int g = 0; g < NG; ++g) {
#pragma unroll
        for (int k = 0; k < NTAP; ++k) {
            int roff;
            if (MODE == M_S1)      roff = k;
            else if (MODE == M_S2) roff = (k == 0) ? 66 : (k == 1) ? 0 : (k == 2) ? 67 : 1;
            else                   roff = g + k;
            const bf16* Ab = wt + (size_t)(g * NTAP + k) * COUT * CIN;
#pragma unroll
            for (int ks = 0; ks < KS; ++ks) {
                s16x8 af[2];
#pragma unroll
                for (int cf = 0; cf < 2; ++cf)
                    af[cf] = *(const s16x8*)(Ab + (co0 + cf * 16 + lr) * CIN + ks * 32 + kg * 8);
                s16x8 bfr[WL];
#pragma unroll
                for (int lf = 0; lf < WL; ++lf) {
                    int t = roff + lw0 + lf * 16 + lr;
                    int byte = ((t * CIN + ks * 32 + kg * 8) << 1) ^ ((t & 7) << 4);
                    bfr[lf] = *(const s16x8*)((const char*)sX + byte);
                }
#pragma unroll
                for (int cf = 0; cf < 2; ++cf)
#pragma unroll
                    for (int lf = 0; lf < WL; ++lf)
                        acc[g][cf][lf] = MFMA16(af[cf], bfr[lf], acc[g][cf][lf]);
            }
        }
    }

#pragma unroll
    for (int g = 0; g < NG; ++g)
#pragma unroll
        for (int cf = 0; cf < 2; ++cf)
#pragma unroll
            for (int lf = 0; lf < WL; ++lf) {
                int cb0  = co0 + cf * 16 + kg * 4;
                int lcol = lw0 + lf * 16 + lr;
                int gcol = (MODE == M_CT) ? (2 * (l0 + lcol) + g) : (l0 + lcol);
                float r[4];
#pragma unroll
                for (int j = 0; j < 4; ++j) {
                    r[j] = acc[g][cf][lf][j];
                    if (HAS_BIAS) r[j] += bias[cb0 + j];
                    if (RELU_OUT) r[j] = fmaxf(r[j], 0.f);
                }
                bf16* po = out + ((size_t)b * Lout + gcol) * COUT + cb0;
                uint2 pk;
                pk.x = (unsigned)bfbits(r[0]) | ((unsigned)bfbits(r[1]) << 16);
                pk.y = (unsigned)bfbits(r[2]) | ((unsigned)bfbits(r[3]) << 16);
                *(uint2*)po = pk;
            }
}

// Fused residual block: x + W2 * relu(W1 * relu(x)) [, relu at stack end].
// in/out (b,1024,128) bf16. w1t [tap][64][128], w2t [128][64].
template<bool RELU_OUT>
__global__ __launch_bounds__(256) void fres_k(
    const bf16* __restrict__ in, const bf16* __restrict__ w1t,
    const bf16* __restrict__ w2t, bf16* __restrict__ out)
{
    __shared__ bf16 sX[66 * 128];
    __shared__ bf16 sH[64 * 64];
    const int tid = threadIdx.x;
    const int b   = blockIdx.y;
    const int l0  = blockIdx.x * 64;
    const bf16* inb = in + (size_t)b * 1024 * 128;

    for (int i = tid; i < 66 * 16; i += 256) {
        int t = i >> 4, c0 = (i & 15) * 8;
        int g = l0 + t - 1;
        s16x8 v = {};
        if (g >= 0 && g < 1024) v = *(const s16x8*)(inb + (size_t)g * 128 + c0);
        int byte = ((t * 128 + c0) << 1) ^ ((t & 7) << 4);
        *(s16x8*)((char*)sX + byte) = v;   // raw (residual needs un-relu'd x)
    }
    __syncthreads();

    const int lane = tid & 63;
    const int wid  = __builtin_amdgcn_readfirstlane(tid >> 6);
    const int lr   = lane & 15;
    const int kg   = lane >> 4;

    // ---- stage 1: 3-tap 128->64, relu on inputs, relu on output -> sH ----
    {
        const int co0 = (wid & 1) * 32;
        const int lw0 = (wid >> 1) * 32;
        f32x4 acc[2][2];
#pragma unroll
        for (int cf = 0; cf < 2; ++cf)
#pragma unroll
            for (int lf = 0; lf < 2; ++lf) acc[cf][lf] = (f32x4){0.f, 0.f, 0.f, 0.f};
#pragma unroll
        for (int k = 0; k < 3; ++k) {
            const bf16* Ab = w1t + (size_t)k * 64 * 128;
#pragma unroll
            for (int ks = 0; ks < 4; ++ks) {
                s16x8 af[2];
#pragma unroll
                for (int cf = 0; cf < 2; ++cf)
                    af[cf] = *(const s16x8*)(Ab + (co0 + cf * 16 + lr) * 128 + ks * 32 + kg * 8);
                s16x8 bfr[2];
#pragma unroll
                for (int lf = 0; lf < 2; ++lf) {
                    int t = k + lw0 + lf * 16 + lr;
                    int byte = ((t * 128 + ks * 32 + kg * 8) << 1) ^ ((t & 7) << 4);
                    bfr[lf] = relu8(*(const s16x8*)((const char*)sX + byte));
                }
#pragma unroll
                for (int cf = 0; cf < 2; ++cf)
#pragma unroll
                    for (int lf = 0; lf < 2; ++lf)
                        acc[cf][lf] = MFMA16(af[cf], bfr[lf], acc[cf][lf]);
            }
        }
#pragma unroll
        for (int cf = 0; cf < 2; ++cf)
#pragma unroll
            for (int lf = 0; lf < 2; ++lf) {
                int pos = lw0 + lf * 16 + lr;
                int ch  = co0 + cf * 16 + kg * 4;
                uint2 pk;
                pk.x = (unsigned)bfbits(fmaxf(acc[cf][lf][0], 0.f)) |
                       ((unsigned)bfbits(fmaxf(acc[cf][lf][1], 0.f)) << 16);
                pk.y = (unsigned)bfbits(fmaxf(acc[cf][lf][2], 0.f)) |
                       ((unsigned)bfbits(fmaxf(acc[cf][lf][3], 0.f)) << 16);
                int byte = ((pos * 64 + ch) << 1) ^ ((pos & 7) << 4);
                *(uint2*)((char*)sH + byte) = pk;
            }
    }
    __syncthreads();

    // ---- stage 2: 1x1 64->128 + residual from sX ----
    {
        const int co0 = wid * 32;
        f32x4 acc2[2][4];
#pragma unroll
        for (int cf = 0; cf < 2; ++cf)
#pragma unroll
            for (int lf = 0; lf < 4; ++lf) acc2[cf][lf] = (f32x4){0.f, 0.f, 0.f, 0.f};
#pragma unroll
        for (int ks = 0; ks < 2; ++ks) {
            s16x8 af[2];
#pragma unroll
            for (int cf = 0; cf < 2; ++cf)
                af[cf] = *(const s16x8*)(w2t + (size_t)(co0 + cf * 16 + lr) * 64 + ks * 32 + kg * 8);
            s16x8 bfr[4];
#pragma unroll
            for (int lf = 0; lf < 4; ++lf) {
                int t = lf * 16 + lr;
                int byte = ((t * 64 + ks * 32 + kg * 8) << 1) ^ ((t & 7) << 4);
                bfr[lf] = *(const s16x8*)((const char*)sH + byte);
            }
#pragma unroll
            for (int cf = 0; cf < 2; ++cf)
#pragma unroll
                for (int lf = 0; lf < 4; ++lf)
                    acc2[cf][lf] = MFMA16(af[cf], bfr[lf], acc2[cf][lf]);
        }
#pragma unroll
        for (int cf = 0; cf < 2; ++cf)
#pragma unroll
            for (int lf = 0; lf < 4; ++lf) {
                int cb0  = co0 + cf * 16 + kg * 4;
                int lcol = lf * 16 + lr;
                int tX   = lcol + 1;
                int rbyte = ((tX * 128 + cb0) << 1) ^ ((tX & 7) << 4);
                uint2 old = *(const uint2*)((const char*)sX + rbyte);
                float r[4];
                r[0] = acc2[cf][lf][0] + bf2f((unsigned short)(old.x & 0xffff));
                r[1] = acc2[cf][lf][1] + bf2f((unsigned short)(old.x >> 16));
                r[2] = acc2[cf][lf][2] + bf2f((unsigned short)(old.y & 0xffff));
                r[3] = acc2[cf][lf][3] + bf2f((unsigned short)(old.y >> 16));
                if (RELU_OUT)
#pragma unroll
                    for (int j = 0; j < 4; ++j) r[j] = fmaxf(r[j], 0.f);
                uint2 pk;
                pk.x = (unsigned)bfbits(r[0]) | ((unsigned)bfbits(r[1]) << 16);
                pk.y = (unsigned)bfbits(r[2]) | ((unsigned)bfbits(r[3]) << 16);
                *(uint2*)(out + ((size_t)b * 1024 + l0 + lcol) * 128 + cb0) = pk;
            }
    }
}

// enc1: 1->64 ch, K=4, s=2, relu; fp32 in, bf16 (b,l,c) out.
__global__ __launch_bounds__(256) void enc1_k(
    const float* __restrict__ x, const float* __restrict__ w,
    const float* __restrict__ bias, bf16* __restrict__ out)
{
    const int tid = threadIdx.x;
    const int b   = blockIdx.y;
    const int l   = blockIdx.x * 256 + tid;
    const float* xb = x + (size_t)b * 4096;
    float xv[4];
#pragma unroll
    for (int k = 0; k < 4; ++k) {
        int g = 2 * l - 1 + k;
        xv[k] = (g >= 0 && g < 4096) ? xb[g] : 0.f;
    }
    bf16* ob = out + ((size_t)b * 2048 + l) * 64;
#pragma unroll
    for (int c0 = 0; c0 < 64; c0 += 8) {
        union { unsigned short u[8]; s16x8 v; } pk;
#pragma unroll
        for (int j = 0; j < 8; ++j) {
            int co = c0 + j;
            float a = bias[co];
#pragma unroll
            for (int k = 0; k < 4; ++k) a = fmaf(xv[k], w[co * 4 + k], a);
            pk.u[j] = bfbits(fmaxf(a, 0.f));
        }
        *(s16x8*)(ob + c0) = pk.v;
    }
}

// Final convT: 64->1 ch, x2 upsample; (b,l,c) bf16 in, fp32 out.
__global__ __launch_bounds__(256) void ct2_k(
    const bf16* __restrict__ in, const float* __restrict__ w,
    const float* __restrict__ bias, float* __restrict__ out)
{
    __shared__ bf16 sX[258 * 64];
    const int tid = threadIdx.x;
    const int b   = blockIdx.y;
    const int m0  = blockIdx.x * 256;
    const bf16* inb = in + (size_t)b * 2048 * 64;
    for (int i = tid; i < 258 * 8; i += 256) {
        int t = i >> 3, c0 = (i & 7) * 8;
        int g = m0 - 1 + t;
        s16x8 v = {};
        if (g >= 0 && g < 2048) v = *(const s16x8*)(inb + (size_t)g * 64 + c0);
        int byte = ((t * 64 + c0) << 1) ^ ((t & 7) << 4);
        *(s16x8*)((char*)sX + byte) = v;
    }
    __syncthreads();
    float e = bias[0], o = bias[0];
#pragma unroll
    for (int c0 = 0; c0 < 64; c0 += 8) {
        int t0 = tid, t1 = tid + 1, t2 = tid + 2;
        s16x8 vm1 = *(const s16x8*)((char*)sX + (((t0 * 64 + c0) << 1) ^ ((t0 & 7) << 4)));
        s16x8 v0  = *(const s16x8*)((char*)sX + (((t1 * 64 + c0) << 1) ^ ((t1 & 7) << 4)));
        s16x8 vp1 = *(const s16x8*)((char*)sX + (((t2 * 64 + c0) << 1) ^ ((t2 & 7) << 4)));
#pragma unroll
        for (int j = 0; j < 8; ++j) {
            int ci = c0 + j;
            float xm1 = bf2f((unsigned short)vm1[j]);
            float x0  = bf2f((unsigned short)v0[j]);
            float xp1 = bf2f((unsigned short)vp1[j]);
            e = fmaf(x0,  w[ci * 4 + 1], fmaf(xm1, w[ci * 4 + 3], e));
            o = fmaf(xp1, w[ci * 4 + 0], fmaf(x0,  w[ci * 4 + 2], o));
        }
    }
    int m = m0 + tid;
    out[(size_t)b * 4096 + 2 * m]     = e;
    out[(size_t)b * 4096 + 2 * m + 1] = o;
}

// Weight transform: fp32 conv weights -> bf16 [tap][co][ci] matrices.
__global__ __launch_bounds__(256) void wx_k(
    const float* ew2, const float* ew3, const float* er1a, const float* er1b,
    const float* er2a, const float* er2b, const float* pvw, const float* dw1,
    const float* dr1a, const float* dr1b, const float* dr2a, const float* dr2b,
    const float* ct1w, bf16* wb)
{
    const int job = blockIdx.x;
    bf16* dst = wb + (size_t)job * 65536;
    const float* src; int CO, CI, K;
    switch (job) {
        case 0:  src = ew2;  CO = 128; CI = 64;  K = 4; break;
        case 1:  src = ew3;  CO = 128; CI = 128; K = 3; break;
        case 2:  src = er1a; CO = 64;  CI = 128; K = 3; break;
        case 3:  src = er1b; CO = 128; CI = 64;  K = 1; break;
        case 4:  src = er2a; CO = 64;  CI = 128; K = 3; break;
        case 5:  src = er2b; CO = 128; CI = 64;  K = 1; break;
        case 6:  src = pvw;  CO = 64;  CI = 128; K = 1; break;
        case 7:  src = dw1;  CO = 128; CI = 64;  K = 3; break;
        case 8:  src = dr1a; CO = 64;  CI = 128; K = 3; break;
        case 9:  src = dr1b; CO = 128; CI = 64;  K = 1; break;
        case 10: src = dr2a; CO = 64;  CI = 128; K = 3; break;
        case 11: src = dr2b; CO = 128; CI = 64;  K = 1; break;
        default: src = ct1w; CO = 64;  CI = 128; K = 4; break;
    }
    const int tot = CO * CI * K;
    for (int i = blockIdx.y * 256 + threadIdx.x; i < tot; i += gridDim.y * 256) {
        if (job < 12) {
            int k = i / (CO * CI); int r = i - k * CO * CI;
            int co = r / CI; int ci = r - co * CI;
            dst[i] = __float2bfloat16(src[((size_t)co * CI + ci) * K + k]);
        } else {
            const int TAP[4] = {3, 1, 2, 0};   // [We0,We1,Wo0,Wo1]
            int g = i / (64 * 128); int r = i - g * 64 * 128;
            int co = r / 128; int ci = r - co * 128;
            dst[i] = __float2bfloat16(src[((size_t)ci * 64 + co) * 4 + TAP[g]]);
        }
    }
}

// codebook prep: fp32 norms + hi/lo bf16 split
__global__ __launch_bounds__(256) void cbprep_k(
    const float* __restrict__ cb, bf16* __restrict__ cbh, bf16* __restrict__ cbl,
    float* __restrict__ sc)
{
    int k = blockIdx.x * 256 + threadIdx.x;   // grid 2
    const float* c = cb + (size_t)k * 64;
    float s = 0.f;
#pragma unroll
    for (int d = 0; d < 64; ++d) s = fmaf(c[d], c[d], s);
    sc[k] = s;
#pragma unroll
    for (int c0 = 0; c0 < 64; c0 += 8) {
        union { unsigned short u[8]; s16x8 v; } ph, pl;
#pragma unroll
        for (int j = 0; j < 8; ++j) {
            float v = c[c0 + j];
            unsigned short h = bfbits(v);
            ph.u[j] = h;
            pl.u[j] = bfbits(v - bf2f(h));
        }
        *(s16x8*)(cbh + (size_t)k * 64 + c0) = ph.v;
        *(s16x8*)(cbl + (size_t)k * 64 + c0) = pl.v;
    }
}

// Fused pre_vq conv + VQ. A (b,1024,128) relu'd -> q bf16, counts, loss.
__global__ __launch_bounds__(256) void vqf_k(
    const bf16* __restrict__ A, const bf16* __restrict__ pvw,
    const float* __restrict__ pvb, const float* __restrict__ cbf,
    const bf16* __restrict__ cbh, const bf16* __restrict__ cbl,
    const float* __restrict__ sc, bf16* __restrict__ q,
    float* __restrict__ counts, float* __restrict__ loss_sum)
{
    __shared__ s16x8 sMemV[4096];            // 64KB: A tile, then z fp32 tile
    char* sMem = (char*)sMemV;
    __shared__ float sSC[512];
    __shared__ float sHist[512];
    __shared__ int   sBK[256];
    __shared__ float sWS[4];
    const int tid = threadIdx.x;
    sSC[tid] = sc[tid]; sSC[tid + 256] = sc[tid + 256];
    sHist[tid] = 0.f;   sHist[tid + 256] = 0.f;

    const int n0blk = blockIdx.x * 256;
    // ---- stage A tile: 256 pos x 128 ch ----
    for (int i = tid; i < 256 * 16; i += 256) {
        int t = i >> 4, c0 = (i & 15) * 8;
        s16x8 v = *(const s16x8*)(A + (size_t)(n0blk + t) * 128 + c0);
        int byte = ((t * 128 + c0) << 1) ^ ((t & 7) << 4);
        *(s16x8*)(sMem + byte) = v;
    }
    __syncthreads();

    const int lane = tid & 63, wid = tid >> 6;
    const int lr = lane & 15, kg = lane >> 4;
    const int pw0 = wid * 64;
    const f32x4 zf4 = {0.f, 0.f, 0.f, 0.f};

    // ---- pre_vq GEMM: z[64ch] for wave's 64 positions ----
    f32x4 zacc[4][4];
#pragma unroll
    for (int cf = 0; cf < 4; ++cf)
#pragma unroll
        for (int lf = 0; lf < 4; ++lf) zacc[cf][lf] = zf4;
#pragma unroll
    for (int ks = 0; ks < 4; ++ks) {
        s16x8 af[4];
#pragma unroll
        for (int cf = 0; cf < 4; ++cf)
            af[cf] = *(const s16x8*)(pvw + (size_t)(cf * 16 + lr) * 128 + ks * 32 + kg * 8);
        s16x8 bfr[4];
#pragma unroll
        for (int lf = 0; lf < 4; ++lf) {
            int t = pw0 + lf * 16 + lr;
            int byte = ((t * 128 + ks * 32 + kg * 8) << 1) ^ ((t & 7) << 4);
            bfr[lf] = *(const s16x8*)((const char*)sMem + byte);
        }
#pragma unroll
        for (int cf = 0; cf < 4; ++cf)
#pragma unroll
            for (int lf = 0; lf < 4; ++lf)
                zacc[cf][lf] = MFMA16(af[cf], bfr[lf], zacc[cf][lf]);
    }
    __syncthreads();      // all A reads done; sMem becomes z fp32 tile

    // z byte offset: ((pos*64 + ch)*4) ^ ((pos&7)<<5)
#pragma unroll
    for (int cf = 0; cf < 4; ++cf)
#pragma unroll
        for (int lf = 0; lf < 4; ++lf) {
            int pos = pw0 + lf * 16 + lr;
            int ch  = cf * 16 + kg * 4;
            float4 v = make_float4(zacc[cf][lf][0] + pvb[ch],
                                   zacc[cf][lf][1] + pvb[ch + 1],
                                   zacc[cf][lf][2] + pvb[ch + 2],
                                   zacc[cf][lf][3] + pvb[ch + 3]);
            int byte = ((pos * 64 + ch) << 2) ^ ((pos & 7) << 5);
            *(float4*)(sMem + byte) = v;
        }
    __syncthreads();

    // ---- load z fragments (hi/lo bf16 split) ----
    s16x8 bh[4][2], bl[4][2];
#pragma unroll
    for (int lf = 0; lf < 4; ++lf)
#pragma unroll
        for (int ks = 0; ks < 2; ++ks) {
            int t = pw0 + lf * 16 + lr;
            int ch = ks * 32 + kg * 8;
            int byte = ((t * 64 + ch) << 2) ^ ((t & 7) << 5);
            float4 v0 = *(const float4*)(sMem + byte);
            float4 v1 = *(const float4*)(sMem + byte + 16);
            float v[8] = {v0.x, v0.y, v0.z, v0.w, v1.x, v1.y, v1.z, v1.w};
            union { unsigned short u[8]; s16x8 s; } ph, pl;
#pragma unroll
            for (int j = 0; j < 8; ++j) {
                unsigned short h = bfbits(v[j]);
                ph.u[j] = h;
                pl.u[j] = bfbits(v[j] - bf2f(h));
            }
            bh[lf][ks] = ph.s; bl[lf][ks] = pl.s;
        }

    // ---- distance GEMM + register argmin ----
    float bestd[4] = {3.4e38f, 3.4e38f, 3.4e38f, 3.4e38f};
    int   bestk[4] = {0, 0, 0, 0};
#pragma unroll 2
    for (int cf = 0; cf < 32; ++cf) {
        int code = cf * 16 + lr;
        const bf16* ph = cbh + code * 64 + kg * 8;
        const bf16* pl = cbl + code * 64 + kg * 8;
        s16x8 ah0 = *(const s16x8*)ph;
        s16x8 ah1 = *(const s16x8*)(ph + 32);
        s16x8 al0 = *(const s16x8*)pl;
        s16x8 al1 = *(const s16x8*)(pl + 32);
        float s0 = sSC[cf * 16 + kg * 4 + 0];
        float s1 = sSC[cf * 16 + kg * 4 + 1];
        float s2 = sSC[cf * 16 + kg * 4 + 2];
        float s3 = sSC[cf * 16 + kg * 4 + 3];
        int kb = cf * 16 + kg * 4;
#pragma unroll
        for (int lf = 0; lf < 4; ++lf) {
            f32x4 acc = MFMA16(ah0, bh[lf][0], zf4);
            acc = MFMA16(ah1, bh[lf][1], acc);
            acc = MFMA16(al0, bh[lf][0], acc);
            acc = MFMA16(al1, bh[lf][1], acc);
            acc = MFMA16(ah0, bl[lf][0], acc);
            acc = MFMA16(ah1, bl[lf][1], acc);
            float d0 = fmaf(acc[0], -2.f, s0);
            float d1 = fmaf(acc[1], -2.f, s1);
            float d2 = fmaf(acc[2], -2.f, s2);
            float d3 = fmaf(acc[3], -2.f, s3);
            if (d0 < bestd[lf]) { bestd[lf] = d0; bestk[lf] = kb; }
            if (d1 < bestd[lf]) { bestd[lf] = d1; bestk[lf] = kb + 1; }
            if (d2 < bestd[lf]) { bestd[lf] = d2; bestk[lf] = kb + 2; }
            if (d3 < bestd[lf]) { bestd[lf] = d3; bestk[lf] = kb + 3; }
        }
    }
#pragma unroll
    for (int lf = 0; lf < 4; ++lf) {
#pragma unroll
        for (int off = 16; off <= 32; off <<= 1) {
            float od = __shfl_xor(bestd[lf], off, 64);
            int   ok = __shfl_xor(bestk[lf], off, 64);
            if (od < bestd[lf] || (od == bestd[lf] && ok < bestk[lf])) {
                bestd[lf] = od; bestk[lf] = ok;
            }
        }
        if (kg == 0) sBK[wid * 64 + lf * 16 + lr] = bestk[lf];
    }
    __syncthreads();

    // ---- phase 2: q write (bf16), loss (fp32), histogram ----
    const int n = n0blk + tid;
    const int k = sBK[tid];
    atomicAdd(&sHist[k], 1.f);
    float lsum = 0.f;
    const float* qp = cbf + (size_t)k * 64;
#pragma unroll
    for (int c0 = 0; c0 < 64; c0 += 8) {
        int byte = ((tid * 64 + c0) << 2) ^ ((tid & 7) << 5);
        float4 z0 = *(const float4*)(sMem + byte);
        float4 z1 = *(const float4*)(sMem + byte + 16);
        float4 q0 = *(const float4*)(qp + c0);
        float4 q1 = *(const float4*)(qp + c0 + 4);
        float qv[8] = {q0.x, q0.y, q0.z, q0.w, q1.x, q1.y, q1.z, q1.w};
        float zv[8] = {z0.x, z0.y, z0.z, z0.w, z1.x, z1.y, z1.z, z1.w};
        union { unsigned short u[8]; s16x8 v; } pk;
#pragma unroll
        for (int j = 0; j < 8; ++j) {
            float d = qv[j] - zv[j];
            lsum = fmaf(d, d, lsum);
            pk.u[j] = bfbits(qv[j]);
        }
        *(s16x8*)(q + (size_t)n * 64 + c0) = pk.v;
    }
#pragma unroll
    for (int off = 32; off > 0; off >>= 1) lsum += __shfl_down(lsum, off, 64);
    if ((tid & 63) == 0) sWS[tid >> 6] = lsum;
    __syncthreads();
    if (tid == 0) atomicAdd(loss_sum, sWS[0] + sWS[1] + sWS[2] + sWS[3]);
    float c0v = sHist[tid];       if (c0v != 0.f) atomicAdd(&counts[tid], c0v);
    float c1v = sHist[tid + 256]; if (c1v != 0.f) atomicAdd(&counts[tid + 256], c1v);
}

__global__ __launch_bounds__(512) void finalize_k(
    const float* __restrict__ counts, const float* __restrict__ loss_sum,
    float* __restrict__ d_out, int out_size)
{
    __shared__ float ws2[8];
    const int tid = threadIdx.x;
    float p = counts[tid] * (1.f / 131072.f);
    float e = p * logf(p + 1e-10f);
#pragma unroll
    for (int off = 32; off > 0; off >>= 1) e += __shfl_down(e, off, 64);
    const int lane = tid & 63, wid = tid >> 6;
    if (lane == 0) ws2[wid] = e;
    __syncthreads();
    if (tid == 0) {
        float s = 0.f;
        for (int i = 0; i < 8; ++i) s += ws2[i];
        d_out[0] = 1.25f * loss_sum[0] * (1.f / 8388608.f);  // (1+BETA)*mean
        d_out[out_size - 1] = expf(-s);
    }
}

extern "C" void kernel_launch(void* const* d_in, const int* in_sizes, int n_in,
                              void* d_out, int out_size, void* d_ws, size_t ws_size,
                              hipStream_t stream)
{
    const float* x        = (const float*)d_in[0];
    const float* enc_w1   = (const float*)d_in[1];
    const float* enc_b1   = (const float*)d_in[2];
    const float* enc_b2   = (const float*)d_in[4];
    const float* enc_b3   = (const float*)d_in[6];
    const float* pre_vq_b = (const float*)d_in[12];
    const float* cb       = (const float*)d_in[13];
    const float* dec_b1   = (const float*)d_in[15];
    const float* ct1_b    = (const float*)d_in[21];
    const float* ct2_w    = (const float*)d_in[22];
    const float* ct2_b    = (const float*)d_in[23];
    float* out = (float*)d_out;

    char* base = (char*)d_ws;
    bf16*  wb   = (bf16*)base;                            // 13 x 64K bf16 = 1.7MB
    bf16*  Abf  = (bf16*)(base + ((size_t)2   << 20));    // 33.5MB
    bf16*  Bbf  = (bf16*)(base + ((size_t)40  << 20));    // 33.5MB
    bf16*  Qbf  = (bf16*)(base + ((size_t)78  << 20));    // 16.7MB
    bf16*  cbh  = (bf16*)(base + ((size_t)96  << 20));    // 64KB
    bf16*  cbl  = (bf16*)(base + ((size_t)96  << 20) + 65536);
    float* sc   = (float*)(base + ((size_t)96  << 20) + 131072);
    float* cnt  = sc + 512;
    float* lsum = cnt + 512;

    hipMemsetAsync(cnt, 0, 513 * sizeof(float), stream);

    dim3 blk(256);
    dim3 g16(16, 128);

    wx_k<<<dim3(13, 8), blk, 0, stream>>>(
        (const float*)d_in[3], (const float*)d_in[5], (const float*)d_in[7],
        (const float*)d_in[8], (const float*)d_in[9], (const float*)d_in[10],
        (const float*)d_in[11], (const float*)d_in[14], (const float*)d_in[16],
        (const float*)d_in[17], (const float*)d_in[18], (const float*)d_in[19],
        (const float*)d_in[20], wb);
    cbprep_k<<<2, blk, 0, stream>>>(cb, cbh, cbl, sc);

    enc1_k<<<dim3(8, 128), blk, 0, stream>>>(x, enc_w1, enc_b1, Abf);
    gconv_k<64,128,4,M_S2,false,true ,true ><<<g16, blk, 0, stream>>>(
        Abf, wb + 0 * 65536, enc_b2, Bbf, 2048, 1024);
    gconv_k<128,128,3,M_S1,false,false,true ><<<g16, blk, 0, stream>>>(
        Bbf, wb + 1 * 65536, enc_b3, Abf, 1024, 1024);
    fres_k<false><<<g16, blk, 0, stream>>>(Abf, wb + 2 * 65536, wb + 3 * 65536, Bbf);
    fres_k<true ><<<g16, blk, 0, stream>>>(Bbf, wb + 4 * 65536, wb + 5 * 65536, Abf);

    vqf_k<<<512, blk, 0, stream>>>(Abf, wb + 6 * 65536, pre_vq_b, cb,
                                   cbh, cbl, sc, Qbf, cnt, lsum);

    gconv_k<64,128,3,M_S1,false,false,true ><<<g16, blk, 0, stream>>>(
        Qbf, wb + 7 * 65536, dec_b1, Abf, 1024, 1024);
    fres_k<false><<<g16, blk, 0, stream>>>(Abf, wb + 8 * 65536, wb + 9 * 65536, Bbf);
    fres_k<true ><<<g16, blk, 0, stream>>>(Bbf, wb + 10 * 65536, wb + 11 * 65536, Abf);
    gconv_k<128,64,2,M_CT,false,true ,true ><<<g16, blk, 0, stream>>>(
        Abf, wb + 12 * 65536, ct1_b, Bbf, 1024, 2048);

    ct2_k<<<dim3(8, 128), blk, 0, stream>>>(Bbf, ct2_w, ct2_b, out + 1);
    finalize_k<<<1, 512, 0, stream>>>(cnt, lsum, out, out_size);
}